// Round 5
// baseline (3264.856 us; speedup 1.0000x reference)
//
#include <hip/hip_runtime.h>
#include <math.h>

// Problem dims
#define NB   16
#define NC   1024
#define ND   256
#define NT_  9
#define TDIM 32

// k_agg tile config: 128x64, BK=32, 256 threads (4 waves, 2x2), dbuf LDS.
#define BM 128
#define BN 64
#define BK 32
#define NTHR 256

typedef _Float16 half8 __attribute__((ext_vector_type(8)));
typedef _Float16 half4v __attribute__((ext_vector_type(4)));
typedef float f32x4 __attribute__((ext_vector_type(4)));

#define GLL(gp, lp)                                                            \
  __builtin_amdgcn_global_load_lds(                                            \
      (const __attribute__((address_space(1))) void*)(gp),                     \
      (__attribute__((address_space(3))) void*)(lp), 16, 0, 0)

// ---------------------------------------------------------------------------
__global__ __launch_bounds__(256) void k_copy_h0(const float* __restrict__ h0,
                                                 float* __restrict__ out) {
  size_t idx = (size_t)blockIdx.x * blockDim.x + threadIdx.x;
  size_t fe = idx * 4;
  size_t b = fe / ((size_t)NC * ND);
  size_t rem = fe % ((size_t)NC * ND);
  float4 v = *(const float4*)(h0 + fe);
  *(float4*)(out + (b * NT_) * (size_t)NC * ND + rem) = v;
}

// ---------------------------------------------------------------------------
__global__ __launch_bounds__(256) void k_deg(const float* __restrict__ adj,
                                             float* __restrict__ invdeg) {
  int wave = threadIdx.x >> 6;
  int lane = threadIdx.x & 63;
  int row = blockIdx.x * 4 + wave;
  const float* p = adj + (size_t)row * NC;
  float s = 0.f;
#pragma unroll
  for (int q = 0; q < 4; ++q) {
    float4 v = *(const float4*)(p + q * 256 + lane * 4);
    s += v.x + v.y + v.z + v.w;
  }
#pragma unroll
  for (int off = 32; off; off >>= 1) s += __shfl_down(s, off);
  if (lane == 0) invdeg[row] = 1.f / fmaxf(s, 1.f);
}

// ---------------------------------------------------------------------------
__global__ __launch_bounds__(256) void k_split_adj(const float* __restrict__ adj,
                                                   _Float16* __restrict__ aH) {
  size_t i4 = (size_t)blockIdx.x * 256 + threadIdx.x;
  float4 v = *(const float4*)(adj + i4 * 4);
  half4v h;
  h[0] = (_Float16)v.x; h[1] = (_Float16)v.y;
  h[2] = (_Float16)v.z; h[3] = (_Float16)v.w;
  *(half4v*)(aH + i4 * 4) = h;
}

// ---------------------------------------------------------------------------
__global__ __launch_bounds__(256) void k_split_w(const float* __restrict__ W1,
                                                 const float* __restrict__ W2,
                                                 _Float16* __restrict__ W1TH,
                                                 _Float16* __restrict__ W1TL,
                                                 _Float16* __restrict__ W2TH,
                                                 _Float16* __restrict__ W2TL) {
  int o = blockIdx.x * 256 + threadIdx.x;
  if (o < 256 * 512) {
    int n = o >> 9, k = o & 511;
    float v = W1[(size_t)k * ND + n];
    _Float16 h = (_Float16)v;
    W1TH[o] = h;
    W1TL[o] = (_Float16)(v - (float)h);
  } else {
    int o2 = o - 256 * 512;
    int n = o2 >> 8, k = o2 & 255;
    float v = W2[(size_t)k * ND + n];
    _Float16 h = (_Float16)v;
    W2TH[o2] = h;
    W2TL[o2] = (_Float16)(v - (float)h);
  }
}

// ---------------------------------------------------------------------------
// one-time: h0 -> hH/hL [b][c][d] + hTH [b][d][c]
__global__ __launch_bounds__(256) void k_htsplit(const float* __restrict__ src,
                                                 _Float16* __restrict__ hH,
                                                 _Float16* __restrict__ hL,
                                                 _Float16* __restrict__ hTH) {
  __shared__ _Float16 tile[64][65];
  int b = blockIdx.z, c0 = blockIdx.x * 64, d0 = blockIdx.y * 64;
  int t = threadIdx.x;
#pragma unroll
  for (int it = 0; it < 16; ++it) {
    int e = it * 256 + t;
    int cl = e >> 6, dl = e & 63;
    float v = src[((size_t)b * NC + c0 + cl) * ND + d0 + dl];
    _Float16 h = (_Float16)v;
    _Float16 lo = (_Float16)(v - (float)h);
    size_t ni = ((size_t)b * NC + c0 + cl) * ND + d0 + dl;
    hH[ni] = h;
    hL[ni] = lo;
    tile[dl][cl] = h;
  }
  __syncthreads();
#pragma unroll
  for (int it = 0; it < 16; ++it) {
    int e = it * 256 + t;
    int dl = e >> 6, cl = e & 63;
    size_t ti = ((size_t)b * ND + d0 + dl) * NC + c0 + cl;
    hTH[ti] = tile[dl][cl];
  }
}

// ---------------------------------------------------------------------------
// 256-thread staging: ROWS x 32 K-major rows -> plane-major chunks [g][row][8]
template <int ROWS>
__device__ __forceinline__ void stage_t(const _Float16* src, long stride,
                                        _Float16* dst, int wid, int lane) {
#pragma unroll
  for (int c = 0; c < ROWS / 64; ++c) {
    int nb = c * 256 + wid * 64;
    int n = nb + lane;
    int g = n / ROWS, r = n % ROWS;
    GLL(src + (size_t)r * stride + 8 * g, dst + (size_t)nb * 8);
  }
}

// single-product MFMA step for k_agg (A 128 rows, B 64 rows, 4x2 frags)
__device__ __forceinline__ void mfma_1p(const _Float16* As, const _Float16* Bs,
                                        int wm, int wn, int lane, f32x4 acc[4][2]) {
  int g = lane >> 4, r = lane & 15;
  half8 Af[4], Bf[2];
#pragma unroll
  for (int i = 0; i < 4; ++i)
    Af[i] = ((const half8*)As)[g * 128 + wm * 64 + i * 16 + r];
#pragma unroll
  for (int j = 0; j < 2; ++j)
    Bf[j] = ((const half8*)Bs)[g * 64 + wn * 32 + j * 16 + r];
#pragma unroll
  for (int i = 0; i < 4; ++i)
#pragma unroll
    for (int j = 0; j < 2; ++j)
      acc[i][j] = __builtin_amdgcn_mfma_f32_16x16x32_f16(Af[i], Bf[j], acc[i][j], 0, 0, 0);
}

// ---------------------------------------------------------------------------
// GEMM1 (fp16 single-product): agg[b] = diag(invdeg[b]) * (adjH[b] @ h[b])
// 1-D grid 512 with XCD-grouping swizzle: the 8 m-blocks sharing one hT panel
// get block ids congruent mod 8 -> same XCD -> panel L2-hits.
__global__ __launch_bounds__(NTHR) void k_agg(const _Float16* __restrict__ adjH,
                                              const _Float16* __restrict__ hTH,
                                              const float* __restrict__ invdeg,
                                              _Float16* __restrict__ aggH,
                                              _Float16* __restrict__ aggL) {
  int p = blockIdx.x;
  int xcd = p & 7, slot = p >> 3;     // slot 0..63
  int m_t = slot & 7;                 // 8 m-tiles
  int g4 = xcd + 8 * (slot >> 3);     // 64 (n,b) groups
  int n_t = g4 & 3;
  int b = g4 >> 2;
  const int m0 = m_t * BM;
  const int n0 = n_t * BN;
  __shared__ __align__(16) _Float16 As[2][BM * BK];
  __shared__ __align__(16) _Float16 Bs[2][BN * BK];
  const int tid = threadIdx.x;
  const int lane = tid & 63, wid = tid >> 6;
  const int wm = wid >> 1, wn = wid & 1;
  f32x4 acc[4][2] = {};
  const _Float16* A = adjH + (size_t)b * NC * NC + (size_t)m0 * NC;
  const _Float16* Bp = hTH + (size_t)b * ND * NC + (size_t)n0 * NC;
  const int NTILES = NC / BK; // 32
  stage_t<BM>(A, NC, As[0], wid, lane);
  stage_t<BN>(Bp, NC, Bs[0], wid, lane);
  __syncthreads();
  for (int t = 0; t < NTILES; ++t) {
    int cur = t & 1;
    if (t + 1 < NTILES) {
      int k0 = (t + 1) * BK;
      stage_t<BM>(A + k0, NC, As[cur ^ 1], wid, lane);
      stage_t<BN>(Bp + k0, NC, Bs[cur ^ 1], wid, lane);
    }
    mfma_1p(As[cur], Bs[cur], wm, wn, lane, acc);
    __syncthreads();
  }
  int r15 = lane & 15, rg = (lane >> 4) * 4;
#pragma unroll
  for (int i = 0; i < 4; ++i) {
#pragma unroll
    for (int j = 0; j < 2; ++j) {
      int col = n0 + wn * 32 + j * 16 + r15;
#pragma unroll
      for (int q = 0; q < 4; ++q) {
        int m = m0 + wm * 64 + i * 16 + rg + q;
        float v = acc[i][j][q] * invdeg[b * NC + m];
        _Float16 h = (_Float16)v;
        size_t idx = ((size_t)b * NC + m) * ND + col;
        aggH[idx] = h;
        aggL[idx] = (_Float16)(v - (float)h);
      }
    }
  }
}

// ---------------------------------------------------------------------------
// fused MLP + RK4: 512 threads, 8 waves (2m x 4n), block tile 64 x 256 (full N)
// phase A: u = tanh([h|agg] @ W1 + b1eff)  (3-product, K=512), u -> LDS (hi fp16)
// phase B: f = u @ W2 + b2                 (2-product: u single x W2 hi/lo)
// epilogue: RK4 stage update, writes hH/hL/hTH in place + traj out
__device__ __forceinline__ void f_stageA(const _Float16* sH, const _Float16* sL,
                                         long stride, _Float16* dH, _Float16* dL,
                                         int wid, int lane) {
  const _Float16* s = (wid < 4) ? sH : sL;
  _Float16* d = (wid < 4) ? dH : dL;
  int w4 = wid & 3; // plane
  GLL(s + (size_t)lane * stride + 8 * w4, d + (size_t)(w4 * 64) * 8);
}

__device__ __forceinline__ void f_stageB(const _Float16* sH, const _Float16* sL,
                                         long stride, _Float16* dH, _Float16* dL,
                                         int wid, int lane) {
  const _Float16* s = (wid < 4) ? sH : sL;
  _Float16* d = (wid < 4) ? dH : dL;
  int w4 = wid & 3;
#pragma unroll
  for (int c = 0; c < 4; ++c) {
    int nb = c * 256 + w4 * 64; // chunk base; g = c, rows w4*64+lane
    GLL(s + (size_t)(w4 * 64 + lane) * stride + 8 * c, d + (size_t)nb * 8);
  }
}

__device__ __forceinline__ void f_mfmaA(const _Float16* AsH, const _Float16* AsL,
                                        const _Float16* BsH, const _Float16* BsL,
                                        int wm, int wn, int lane, f32x4 acc[2][4]) {
  int g = lane >> 4, r = lane & 15;
  half8 AH[2], AL[2], BH[4], BL[4];
#pragma unroll
  for (int i = 0; i < 2; ++i) {
    int ch = g * 64 + wm * 32 + i * 16 + r;
    AH[i] = ((const half8*)AsH)[ch];
    AL[i] = ((const half8*)AsL)[ch];
  }
#pragma unroll
  for (int j = 0; j < 4; ++j) {
    int ch = g * 256 + wn * 64 + j * 16 + r;
    BH[j] = ((const half8*)BsH)[ch];
    BL[j] = ((const half8*)BsL)[ch];
  }
#pragma unroll
  for (int i = 0; i < 2; ++i)
#pragma unroll
    for (int j = 0; j < 4; ++j) {
      acc[i][j] = __builtin_amdgcn_mfma_f32_16x16x32_f16(AH[i], BH[j], acc[i][j], 0, 0, 0);
      acc[i][j] = __builtin_amdgcn_mfma_f32_16x16x32_f16(AH[i], BL[j], acc[i][j], 0, 0, 0);
      acc[i][j] = __builtin_amdgcn_mfma_f32_16x16x32_f16(AL[i], BH[j], acc[i][j], 0, 0, 0);
    }
}

__device__ __forceinline__ void f_mfmaB(const _Float16* uS, int k0,
                                        const _Float16* BsH, const _Float16* BsL,
                                        int wm, int wn, int lane, f32x4 acc[2][4]) {
  int g = lane >> 4, r = lane & 15;
  half8 Af[2], BH[4], BL[4];
#pragma unroll
  for (int i = 0; i < 2; ++i) {
    int row = wm * 32 + i * 16 + r;
    Af[i] = *(const half8*)(uS + row * 264 + k0 + g * 8);
  }
#pragma unroll
  for (int j = 0; j < 4; ++j) {
    int ch = g * 256 + wn * 64 + j * 16 + r;
    BH[j] = ((const half8*)BsH)[ch];
    BL[j] = ((const half8*)BsL)[ch];
  }
#pragma unroll
  for (int i = 0; i < 2; ++i)
#pragma unroll
    for (int j = 0; j < 4; ++j) {
      acc[i][j] = __builtin_amdgcn_mfma_f32_16x16x32_f16(Af[i], BH[j], acc[i][j], 0, 0, 0);
      acc[i][j] = __builtin_amdgcn_mfma_f32_16x16x32_f16(Af[i], BL[j], acc[i][j], 0, 0, 0);
    }
}

__global__ __launch_bounds__(512) void k_fused(
    const _Float16* __restrict__ hH, const _Float16* __restrict__ hL,
    const _Float16* __restrict__ aggH, const _Float16* __restrict__ aggL,
    const _Float16* __restrict__ W1TH, const _Float16* __restrict__ W1TL,
    const _Float16* __restrict__ W2TH, const _Float16* __restrict__ W2TL,
    const float* __restrict__ W1, const float* __restrict__ b1,
    const float* __restrict__ b2, const float* __restrict__ tg,
    int step, int stage, float* __restrict__ out, float* __restrict__ accws,
    _Float16* __restrict__ hHo, _Float16* __restrict__ hLo,
    _Float16* __restrict__ hTo) {
  __shared__ __align__(16) _Float16 AsH[2][64 * BK];
  __shared__ __align__(16) _Float16 AsL[2][64 * BK];
  __shared__ __align__(16) _Float16 BsH[2][256 * BK];
  __shared__ __align__(16) _Float16 BsL[2][256 * BK];
  __shared__ _Float16 uS[64 * 264];
  __shared__ float te_s[TDIM];
  __shared__ float b1s[256];

  const int tid = threadIdx.x;
  const int lane = tid & 63, wid = tid >> 6;
  const int wm = wid >> 2, wn = wid & 3; // 2 x 4 waves
  const int m0 = blockIdx.x * 64;
  const int b = m0 >> 10;
  const size_t abase = ((size_t)b * NC + (m0 & 1023)) * ND;

  f32x4 acc[2][4] = {};

  if (tid < 16) {
    float t0 = tg[step], t1 = tg[step + 1];
    float frac = (stage == 0) ? 0.f : ((stage == 3) ? 1.f : 0.5f);
    float t = t0 + frac * (t1 - t0);
    float f = expf(-logf(10000.f) * (float)tid / 16.f);
    te_s[tid] = sinf(t * f);
    te_s[tid + 16] = cosf(t * f);
  }
  // prologue: stage tile 0
  f_stageA(hH + abase, hL + abase, ND, AsH[0], AsL[0], wid, lane);
  f_stageB(W1TH, W1TL, 512, BsH[0], BsL[0], wid, lane);
  __syncthreads();
  if (tid < 256) {
    float s = b1[tid];
#pragma unroll
    for (int q = 0; q < TDIM; ++q)
      s = fmaf(te_s[q], W1[(size_t)(512 + q) * ND + tid], s);
    b1s[tid] = s;
  }
  // phase A: K = 512 over [h | agg]
  for (int t = 0; t < 16; ++t) {
    int cur = t & 1;
    if (t + 1 < 16) {
      int k0 = (t + 1) * BK;
      const _Float16 *sH, *sL;
      if (k0 < 256) { sH = hH + abase + k0;          sL = hL + abase + k0; }
      else          { sH = aggH + abase + (k0-256);  sL = aggL + abase + (k0-256); }
      f_stageA(sH, sL, ND, AsH[cur ^ 1], AsL[cur ^ 1], wid, lane);
      f_stageB(W1TH + k0, W1TL + k0, 512, BsH[cur ^ 1], BsL[cur ^ 1], wid, lane);
    }
    f_mfmaA(AsH[cur], AsL[cur], BsH[cur], BsL[cur], wm, wn, lane, acc);
    __syncthreads();
  }
  // transition: stage W2 tile 0 (into Bs[0], free now), write u to LDS
  f_stageB(W2TH, W2TL, 256, BsH[0], BsL[0], wid, lane);
  {
    int r15 = lane & 15, rg = (lane >> 4) * 4;
#pragma unroll
    for (int i = 0; i < 2; ++i)
#pragma unroll
      for (int j = 0; j < 4; ++j) {
        int col = wn * 64 + j * 16 + r15;
        int row = wm * 32 + i * 16 + rg;
#pragma unroll
        for (int q = 0; q < 4; ++q) {
          float v = tanhf(acc[i][j][q] + b1s[col]);
          uS[(row + q) * 264 + col] = (_Float16)v;
        }
        acc[i][j] = (f32x4){0.f, 0.f, 0.f, 0.f};
      }
  }
  __syncthreads();
  // phase B: K = 256 over u
  for (int t = 0; t < 8; ++t) {
    int cur = t & 1;
    if (t + 1 < 8) {
      int k0 = (t + 1) * BK;
      f_stageB(W2TH + k0, W2TL + k0, 256, BsH[cur ^ 1], BsL[cur ^ 1], wid, lane);
    }
    f_mfmaB(uS, t * BK, BsH[cur], BsL[cur], wm, wn, lane, acc);
    __syncthreads();
  }
  // RK4 epilogue
  const float t0 = tg[step], t1 = tg[step + 1];
  const float dt = t1 - t0;
  const float cs = (stage == 2) ? dt : 0.5f * dt;
  int r15 = lane & 15, rg = (lane >> 4) * 4;
#pragma unroll
  for (int i = 0; i < 2; ++i) {
#pragma unroll
    for (int j = 0; j < 4; ++j) {
      int col = wn * 64 + j * 16 + r15;
      float bb2 = b2[col];
      int mbase = m0 + wm * 32 + i * 16 + rg; // multiple of 4, same b
      int ii0 = mbase & 1023;
      size_t hrow = (((size_t)b * NT_ + step) * NC + ii0) * (size_t)ND + col;
      size_t wrow = (size_t)mbase * ND + col;
      float val[4];
#pragma unroll
      for (int q = 0; q < 4; ++q) {
        float f = acc[i][j][q] + bb2;
        float hb = out[hrow + (size_t)q * ND];
        size_t widx = wrow + (size_t)q * ND;
        if (stage == 0) {
          accws[widx] = f;
          val[q] = hb + cs * f;
        } else if (stage == 3) {
          float hn = hb + (dt / 6.f) * (accws[widx] + f);
          out[hrow + (size_t)NC * ND + (size_t)q * ND] = hn; // traj[:,step+1]
          val[q] = hn;
        } else {
          accws[widx] += 2.f * f;
          val[q] = hb + cs * f;
        }
      }
      half4v th;
#pragma unroll
      for (int q = 0; q < 4; ++q) {
        _Float16 hh = (_Float16)val[q];
        th[q] = hh;
        size_t ni = ((size_t)b * NC + ii0 + q) * ND + col;
        hHo[ni] = hh;
        hLo[ni] = (_Float16)(val[q] - (float)hh);
      }
      size_t trow = ((size_t)b * ND + col) * NC + ii0;
      *(half4v*)(hTo + trow) = th;
    }
  }
}

// ---------------------------------------------------------------------------
extern "C" void kernel_launch(void* const* d_in, const int* in_sizes, int n_in,
                              void* d_out, int out_size, void* d_ws, size_t ws_size,
                              hipStream_t stream) {
  const float* h0 = (const float*)d_in[0];
  const float* tg = (const float*)d_in[1];
  const float* adj = (const float*)d_in[2];
  const float* W1 = (const float*)d_in[3];
  const float* b1 = (const float*)d_in[4];
  const float* W2 = (const float*)d_in[5];
  const float* b2 = (const float*)d_in[6];
  float* out = (float*)d_out;

  const size_t CD = (size_t)NC * ND; // 262144
  char* w = (char*)d_ws;
  float* invdeg = (float*)w;     w += (size_t)16384 * 4;
  float* accws = (float*)w;      w += (size_t)NB * CD * 4;
  _Float16* adjH = (_Float16*)w; w += (size_t)NB * NC * NC * 2;
  _Float16* hH = (_Float16*)w;   w += (size_t)NB * CD * 2;
  _Float16* hL = (_Float16*)w;   w += (size_t)NB * CD * 2;
  _Float16* hTH = (_Float16*)w;  w += (size_t)NB * CD * 2;
  _Float16* aggH = (_Float16*)w; w += (size_t)NB * CD * 2;
  _Float16* aggL = (_Float16*)w; w += (size_t)NB * CD * 2;
  _Float16* W1TH = (_Float16*)w; w += (size_t)256 * 512 * 2;
  _Float16* W1TL = (_Float16*)w; w += (size_t)256 * 512 * 2;
  _Float16* W2TH = (_Float16*)w; w += (size_t)256 * 256 * 2;
  _Float16* W2TL = (_Float16*)w; w += (size_t)256 * 256 * 2;

  k_copy_h0<<<dim3(4096), dim3(256), 0, stream>>>(h0, out);
  k_deg<<<dim3(4096), dim3(256), 0, stream>>>(adj, invdeg);
  k_split_adj<<<dim3(16384), dim3(256), 0, stream>>>(adj, adjH);
  k_split_w<<<dim3(768), dim3(256), 0, stream>>>(W1, W2, W1TH, W1TL, W2TH, W2TL);
  k_htsplit<<<dim3(16, 4, 16), dim3(256), 0, stream>>>(h0, hH, hL, hTH);

  for (int s = 0; s < NT_ - 1; ++s) {
    for (int st = 0; st < 4; ++st) {
      k_agg<<<dim3(512), dim3(NTHR), 0, stream>>>(adjH, hTH, invdeg, aggH, aggL);
      k_fused<<<dim3(256), dim3(512), 0, stream>>>(hH, hL, aggH, aggL, W1TH, W1TL,
                                                   W2TH, W2TL, W1, b1, b2, tg, s, st,
                                                   out, accws, hH, hL, hTH);
    }
  }
}

// Round 6
// 3058.847 us; speedup vs baseline: 1.0673x; 1.0673x over previous
//
#include <hip/hip_runtime.h>
#include <math.h>

// Problem dims
#define NB   16
#define NC   1024
#define ND   256
#define NT_  9
#define TDIM 32
#define BK   32

typedef _Float16 half8 __attribute__((ext_vector_type(8)));
typedef _Float16 half4v __attribute__((ext_vector_type(4)));
typedef float f32x4 __attribute__((ext_vector_type(4)));

#define GLL(gp, lp)                                                            \
  __builtin_amdgcn_global_load_lds(                                            \
      (const __attribute__((address_space(1))) void*)(gp),                     \
      (__attribute__((address_space(3))) void*)(lp), 16, 0, 0)

#define MFMA16(A, B, C) __builtin_amdgcn_mfma_f32_16x16x32_f16(A, B, C, 0, 0, 0)

// ---------------------------------------------------------------------------
__global__ __launch_bounds__(256) void k_copy_h0(const float* __restrict__ h0,
                                                 float* __restrict__ out) {
  size_t idx = (size_t)blockIdx.x * blockDim.x + threadIdx.x;
  size_t fe = idx * 4;
  size_t b = fe / ((size_t)NC * ND);
  size_t rem = fe % ((size_t)NC * ND);
  float4 v = *(const float4*)(h0 + fe);
  *(float4*)(out + (b * NT_) * (size_t)NC * ND + rem) = v;
}

// ---------------------------------------------------------------------------
__global__ __launch_bounds__(256) void k_deg(const float* __restrict__ adj,
                                             float* __restrict__ invdeg) {
  int wave = threadIdx.x >> 6;
  int lane = threadIdx.x & 63;
  int row = blockIdx.x * 4 + wave;
  const float* p = adj + (size_t)row * NC;
  float s = 0.f;
#pragma unroll
  for (int q = 0; q < 4; ++q) {
    float4 v = *(const float4*)(p + q * 256 + lane * 4);
    s += v.x + v.y + v.z + v.w;
  }
#pragma unroll
  for (int off = 32; off; off >>= 1) s += __shfl_down(s, off);
  if (lane == 0) invdeg[row] = 1.f / fmaxf(s, 1.f);
}

// ---------------------------------------------------------------------------
__global__ __launch_bounds__(256) void k_split_adj(const float* __restrict__ adj,
                                                   _Float16* __restrict__ aH) {
  size_t i4 = (size_t)blockIdx.x * 256 + threadIdx.x;
  float4 v = *(const float4*)(adj + i4 * 4);
  half4v h;
  h[0] = (_Float16)v.x; h[1] = (_Float16)v.y;
  h[2] = (_Float16)v.z; h[3] = (_Float16)v.w;
  *(half4v*)(aH + i4 * 4) = h;
}

// ---------------------------------------------------------------------------
__global__ __launch_bounds__(256) void k_split_w(const float* __restrict__ W1,
                                                 const float* __restrict__ W2,
                                                 _Float16* __restrict__ W1TH,
                                                 _Float16* __restrict__ W1TL,
                                                 _Float16* __restrict__ W2TH,
                                                 _Float16* __restrict__ W2TL) {
  int o = blockIdx.x * 256 + threadIdx.x;
  if (o < 256 * 512) {
    int n = o >> 9, k = o & 511;
    float v = W1[(size_t)k * ND + n];
    _Float16 h = (_Float16)v;
    W1TH[o] = h;
    W1TL[o] = (_Float16)(v - (float)h);
  } else {
    int o2 = o - 256 * 512;
    int n = o2 >> 8, k = o2 & 255;
    float v = W2[(size_t)k * ND + n];
    _Float16 h = (_Float16)v;
    W2TH[o2] = h;
    W2TL[o2] = (_Float16)(v - (float)h);
  }
}

// ---------------------------------------------------------------------------
// one-time: h0 -> hH/hL [b][c][d] + hT [b][d][c] (hi only)
__global__ __launch_bounds__(256) void k_htsplit(const float* __restrict__ src,
                                                 _Float16* __restrict__ hH,
                                                 _Float16* __restrict__ hL,
                                                 _Float16* __restrict__ hT) {
  __shared__ _Float16 tile[64][65];
  int b = blockIdx.z, c0 = blockIdx.x * 64, d0 = blockIdx.y * 64;
  int t = threadIdx.x;
#pragma unroll
  for (int it = 0; it < 16; ++it) {
    int e = it * 256 + t;
    int cl = e >> 6, dl = e & 63;
    float v = src[((size_t)b * NC + c0 + cl) * ND + d0 + dl];
    _Float16 h = (_Float16)v;
    _Float16 lo = (_Float16)(v - (float)h);
    size_t ni = ((size_t)b * NC + c0 + cl) * ND + d0 + dl;
    hH[ni] = h;
    hL[ni] = lo;
    tile[dl][cl] = h;
  }
  __syncthreads();
#pragma unroll
  for (int it = 0; it < 16; ++it) {
    int e = it * 256 + t;
    int dl = e >> 6, cl = e & 63;
    size_t ti = ((size_t)b * ND + d0 + dl) * NC + c0 + cl;
    hT[ti] = tile[dl][cl];
  }
}

// ---------------------------------------------------------------------------
// k_stage: one RK4 stage, fully fused. grid 256 (b*16+mq), 512 thr = 8 waves.
// phase0: agg = diag(invdeg) * adj@h (K=1024, 1p) -> LDS aggS (hi/lo)
// phaseA: u = tanh([h|agg] @ W1 + b1eff) (K=512, 3p; W1-lo from L2) -> LDS uS
// phaseB: f = u @ W2 + b2 (K=256, 2p; W2-lo from L2)
// epilogue: RK4 stage update; writes hH/hL in place, hT ping-pong, traj out.
__global__ __launch_bounds__(512) void k_stage(
    const _Float16* __restrict__ adjH,
    _Float16* __restrict__ hH, _Float16* __restrict__ hL,
    const _Float16* __restrict__ hTr, _Float16* __restrict__ hTw,
    const float* __restrict__ invdeg,
    const _Float16* __restrict__ W1TH, const _Float16* __restrict__ W1TL,
    const _Float16* __restrict__ W2TH, const _Float16* __restrict__ W2TL,
    const float* __restrict__ W1, const float* __restrict__ b1,
    const float* __restrict__ b2, const float* __restrict__ tg,
    int step, int stage, float* __restrict__ out, float* __restrict__ accws) {
  __shared__ __align__(16) _Float16 BsH[2][256 * BK];  // 32 KB (W hi / hT hi)
  __shared__ __align__(16) _Float16 AsH[2][64 * BK];   // 8 KB
  __shared__ __align__(16) _Float16 AsL[2][64 * BK];   // 8 KB
  __shared__ __align__(16) _Float16 POOL[32768];       // 64 KB aggS -> uS
  __shared__ float te_s[TDIM];
  __shared__ float b1s[256];
  _Float16* aggSH = POOL;
  _Float16* aggSL = POOL + 16384;
  _Float16* uS = POOL;  // alias, live after aggS is dead

  const int tid = threadIdx.x;
  const int lane = tid & 63, wid = tid >> 6;
  const int wm = wid >> 2, wn = wid & 3;  // 2 x 4 waves
  const int g = lane >> 4, r = lane & 15;
  const int rg = g * 4;
  const int blk = blockIdx.x;
  const int b = blk >> 4, mq = blk & 15;
  const int m0 = blk * 64;

  const _Float16* A0 = adjH + ((size_t)b * NC + mq * 64) * NC;  // 64 rows, stride NC
  const _Float16* B0 = hTr + (size_t)b * ND * NC;               // 256 rows, stride NC
  const size_t abase = ((size_t)b * NC + mq * 64) * ND;

  f32x4 acc[2][4] = {};

  // ---- prologue: stage phase0 tile0 + time embedding ----
  if (wid < 4) GLL(A0 + (size_t)lane * NC + 8 * wid, &AsH[0][(wid * 64) * 8]);
#pragma unroll
  for (int c = 0; c < 2; ++c) {
    int qq = wid * 2 + c;
    GLL(B0 + (size_t)((qq & 3) * 64 + lane) * NC + 8 * (qq >> 2),
        &BsH[0][(qq * 64) * 8]);
  }
  if (tid < 16) {
    float t0 = tg[step], t1 = tg[step + 1];
    float frac = (stage == 0) ? 0.f : ((stage == 3) ? 1.f : 0.5f);
    float t = t0 + frac * (t1 - t0);
    float f = expf(-logf(10000.f) * (float)tid / 16.f);
    te_s[tid] = sinf(t * f);
    te_s[tid + 16] = cosf(t * f);
  }
  __syncthreads();
  if (tid < 256) {
    float s = b1[tid];
#pragma unroll
    for (int q = 0; q < TDIM; ++q)
      s = fmaf(te_s[q], W1[(size_t)(512 + q) * ND + tid], s);
    b1s[tid] = s;
  }
  // ---- phase 0: K = 1024, single-product ----
  for (int t = 0; t < 32; ++t) {
    int cur = t & 1;
    if (t + 1 < 32) {
      int k0 = (t + 1) * BK;
      if (wid < 4)
        GLL(A0 + (size_t)lane * NC + 8 * wid + k0, &AsH[cur ^ 1][(wid * 64) * 8]);
#pragma unroll
      for (int c = 0; c < 2; ++c) {
        int qq = wid * 2 + c;
        GLL(B0 + (size_t)((qq & 3) * 64 + lane) * NC + 8 * (qq >> 2) + k0,
            &BsH[cur ^ 1][(qq * 64) * 8]);
      }
    }
    half8 Af[2], Bf[4];
#pragma unroll
    for (int i = 0; i < 2; ++i)
      Af[i] = ((const half8*)AsH[cur])[g * 64 + wm * 32 + i * 16 + r];
#pragma unroll
    for (int j = 0; j < 4; ++j)
      Bf[j] = ((const half8*)BsH[cur])[g * 256 + wn * 64 + j * 16 + r];
#pragma unroll
    for (int i = 0; i < 2; ++i)
#pragma unroll
      for (int j = 0; j < 4; ++j) acc[i][j] = MFMA16(Af[i], Bf[j], acc[i][j]);
    __syncthreads();
  }
  // ---- phase0 epilogue: invdeg scale, split to aggS hi/lo (LDS) ----
#pragma unroll
  for (int i = 0; i < 2; ++i)
#pragma unroll
    for (int j = 0; j < 4; ++j) {
      int d = wn * 64 + j * 16 + r;
#pragma unroll
      for (int q = 0; q < 4; ++q) {
        int lr = wm * 32 + i * 16 + rg + q;
        float v = acc[i][j][q] * invdeg[b * NC + mq * 64 + lr];
        _Float16 hh = (_Float16)v;
        int pos = ((d >> 3) * 64 + lr) * 8 + (d & 7);
        aggSH[pos] = hh;
        aggSL[pos] = (_Float16)(v - (float)hh);
      }
      acc[i][j] = (f32x4){0.f, 0.f, 0.f, 0.f};
    }
  // stage phase A tile0 (h hi/lo + W1 hi)
  {
    const _Float16* s = (wid < 4) ? hH : hL;
    _Float16* dbuf = (wid < 4) ? AsH[0] : AsL[0];
    int w4 = wid & 3;
    GLL(s + abase + (size_t)lane * ND + 8 * w4, dbuf + (w4 * 64) * 8);
#pragma unroll
    for (int c = 0; c < 2; ++c) {
      int qq = wid * 2 + c;
      GLL(W1TH + (size_t)((qq & 3) * 64 + lane) * 512 + 8 * (qq >> 2),
          &BsH[0][(qq * 64) * 8]);
    }
  }
  __syncthreads();
  // ---- phase A: K = 512, 3-product (W1-lo direct from L2) ----
  for (int t = 0; t < 16; ++t) {
    int cur = t & 1;
    if (t + 1 < 16) {
      int k0n = (t + 1) * BK;
      if (t + 1 < 8) {
        const _Float16* s = (wid < 4) ? hH : hL;
        _Float16* dbuf = (wid < 4) ? AsH[cur ^ 1] : AsL[cur ^ 1];
        int w4 = wid & 3;
        GLL(s + abase + (size_t)lane * ND + 8 * w4 + k0n, dbuf + (w4 * 64) * 8);
      }
#pragma unroll
      for (int c = 0; c < 2; ++c) {
        int qq = wid * 2 + c;
        GLL(W1TH + (size_t)((qq & 3) * 64 + lane) * 512 + 8 * (qq >> 2) + k0n,
            &BsH[cur ^ 1][(qq * 64) * 8]);
      }
    }
    half8 AH[2], AL[2], BH[4], BL[4];
    if (t < 8) {
#pragma unroll
      for (int i = 0; i < 2; ++i) {
        int ch = g * 64 + wm * 32 + i * 16 + r;
        AH[i] = ((const half8*)AsH[cur])[ch];
        AL[i] = ((const half8*)AsL[cur])[ch];
      }
    } else {
      int p0 = (t - 8) * 4 + g;
#pragma unroll
      for (int i = 0; i < 2; ++i) {
        int ch = p0 * 64 + wm * 32 + i * 16 + r;
        AH[i] = ((const half8*)aggSH)[ch];
        AL[i] = ((const half8*)aggSL)[ch];
      }
    }
    int k0 = t * BK;
#pragma unroll
    for (int j = 0; j < 4; ++j) {
      int n = wn * 64 + j * 16 + r;
      BH[j] = ((const half8*)BsH[cur])[g * 256 + n];
      BL[j] = *(const half8*)(W1TL + (size_t)n * 512 + k0 + g * 8);
    }
#pragma unroll
    for (int i = 0; i < 2; ++i)
#pragma unroll
      for (int j = 0; j < 4; ++j) {
        acc[i][j] = MFMA16(AH[i], BH[j], acc[i][j]);
        acc[i][j] = MFMA16(AH[i], BL[j], acc[i][j]);
        acc[i][j] = MFMA16(AL[i], BH[j], acc[i][j]);
      }
    __syncthreads();
  }
  // ---- transition: stage W2 hi tile0, write uS (aliases dead aggS) ----
#pragma unroll
  for (int c = 0; c < 2; ++c) {
    int qq = wid * 2 + c;
    GLL(W2TH + (size_t)((qq & 3) * 64 + lane) * 256 + 8 * (qq >> 2),
        &BsH[0][(qq * 64) * 8]);
  }
#pragma unroll
  for (int i = 0; i < 2; ++i)
#pragma unroll
    for (int j = 0; j < 4; ++j) {
      int col = wn * 64 + j * 16 + r;
#pragma unroll
      for (int q = 0; q < 4; ++q) {
        int row = wm * 32 + i * 16 + rg + q;
        uS[row * 264 + col] = (_Float16)tanhf(acc[i][j][q] + b1s[col]);
      }
      acc[i][j] = (f32x4){0.f, 0.f, 0.f, 0.f};
    }
  __syncthreads();
  // ---- phase B: K = 256, 2-product (W2-lo direct from L2) ----
  for (int t = 0; t < 8; ++t) {
    int cur = t & 1;
    if (t + 1 < 8) {
      int k0n = (t + 1) * BK;
#pragma unroll
      for (int c = 0; c < 2; ++c) {
        int qq = wid * 2 + c;
        GLL(W2TH + (size_t)((qq & 3) * 64 + lane) * 256 + 8 * (qq >> 2) + k0n,
            &BsH[cur ^ 1][(qq * 64) * 8]);
      }
    }
    int k0 = t * BK;
    half8 Af[2], BH[4], BL[4];
#pragma unroll
    for (int i = 0; i < 2; ++i)
      Af[i] = *(const half8*)(uS + (wm * 32 + i * 16 + r) * 264 + k0 + g * 8);
#pragma unroll
    for (int j = 0; j < 4; ++j) {
      int n = wn * 64 + j * 16 + r;
      BH[j] = ((const half8*)BsH[cur])[g * 256 + n];
      BL[j] = *(const half8*)(W2TL + (size_t)n * 256 + k0 + g * 8);
    }
#pragma unroll
    for (int i = 0; i < 2; ++i)
#pragma unroll
      for (int j = 0; j < 4; ++j) {
        acc[i][j] = MFMA16(Af[i], BH[j], acc[i][j]);
        acc[i][j] = MFMA16(Af[i], BL[j], acc[i][j]);
      }
    __syncthreads();
  }
  // ---- RK4 epilogue ----
  const float t0 = tg[step], t1 = tg[step + 1];
  const float dt = t1 - t0;
  const float cs = (stage == 2) ? dt : 0.5f * dt;
#pragma unroll
  for (int i = 0; i < 2; ++i) {
#pragma unroll
    for (int j = 0; j < 4; ++j) {
      int col = wn * 64 + j * 16 + r;
      float bb2 = b2[col];
      int mbase = m0 + wm * 32 + i * 16 + rg;  // multiple of 4, same batch
      int ii0 = mbase & 1023;
      size_t hrow = (((size_t)b * NT_ + step) * NC + ii0) * (size_t)ND + col;
      size_t wrow = (size_t)mbase * ND + col;
      float val[4];
#pragma unroll
      for (int q = 0; q < 4; ++q) {
        float f = acc[i][j][q] + bb2;
        float hb = out[hrow + (size_t)q * ND];
        size_t widx = wrow + (size_t)q * ND;
        if (stage == 0) {
          accws[widx] = f;
          val[q] = hb + cs * f;
        } else if (stage == 3) {
          float hn = hb + (dt / 6.f) * (accws[widx] + f);
          out[hrow + (size_t)NC * ND + (size_t)q * ND] = hn;  // traj[:,step+1]
          val[q] = hn;
        } else {
          accws[widx] += 2.f * f;
          val[q] = hb + cs * f;
        }
      }
      half4v th;
#pragma unroll
      for (int q = 0; q < 4; ++q) {
        _Float16 hh = (_Float16)val[q];
        th[q] = hh;
        size_t ni = ((size_t)b * NC + ii0 + q) * ND + col;
        hH[ni] = hh;
        hL[ni] = (_Float16)(val[q] - (float)hh);
      }
      size_t trow = ((size_t)b * ND + col) * NC + ii0;
      *(half4v*)(hTw + trow) = th;
    }
  }
}

// ---------------------------------------------------------------------------
extern "C" void kernel_launch(void* const* d_in, const int* in_sizes, int n_in,
                              void* d_out, int out_size, void* d_ws, size_t ws_size,
                              hipStream_t stream) {
  const float* h0 = (const float*)d_in[0];
  const float* tg = (const float*)d_in[1];
  const float* adj = (const float*)d_in[2];
  const float* W1 = (const float*)d_in[3];
  const float* b1 = (const float*)d_in[4];
  const float* W2 = (const float*)d_in[5];
  const float* b2 = (const float*)d_in[6];
  float* out = (float*)d_out;

  const size_t CD = (size_t)NC * ND;  // 262144
  char* w = (char*)d_ws;
  float* invdeg = (float*)w;     w += (size_t)16384 * 4;
  float* accws = (float*)w;      w += (size_t)NB * CD * 4;
  _Float16* adjH = (_Float16*)w; w += (size_t)NB * NC * NC * 2;
  _Float16* hH = (_Float16*)w;   w += (size_t)NB * CD * 2;
  _Float16* hL = (_Float16*)w;   w += (size_t)NB * CD * 2;
  _Float16* hTa = (_Float16*)w;  w += (size_t)NB * CD * 2;
  _Float16* hTb = (_Float16*)w;  w += (size_t)NB * CD * 2;
  _Float16* W1TH = (_Float16*)w; w += (size_t)256 * 512 * 2;
  _Float16* W1TL = (_Float16*)w; w += (size_t)256 * 512 * 2;
  _Float16* W2TH = (_Float16*)w; w += (size_t)256 * 256 * 2;
  _Float16* W2TL = (_Float16*)w; w += (size_t)256 * 256 * 2;

  k_copy_h0<<<dim3(4096), dim3(256), 0, stream>>>(h0, out);
  k_deg<<<dim3(4096), dim3(256), 0, stream>>>(adj, invdeg);
  k_split_adj<<<dim3(16384), dim3(256), 0, stream>>>(adj, adjH);
  k_split_w<<<dim3(768), dim3(256), 0, stream>>>(W1, W2, W1TH, W1TL, W2TH, W2TL);
  k_htsplit<<<dim3(16, 4, 16), dim3(256), 0, stream>>>(h0, hH, hL, hTa);

  int par = 0;
  for (int s = 0; s < NT_ - 1; ++s) {
    for (int st = 0; st < 4; ++st) {
      k_stage<<<dim3(256), dim3(512), 0, stream>>>(
          adjH, hH, hL, par ? hTb : hTa, par ? hTa : hTb, invdeg, W1TH, W1TL,
          W2TH, W2TL, W1, b1, b2, tg, s, st, out, accws);
      par ^= 1;
    }
  }
}